// Round 6
// baseline (584.131 us; speedup 1.0000x reference)
//
#include <hip/hip_runtime.h>

#define NUC 8.0e-4f   // MIU/(U*L)

typedef __attribute__((ext_vector_type(8))) short   bf16x8;
typedef __attribute__((ext_vector_type(8))) unsigned short u16x8;
typedef __attribute__((ext_vector_type(4))) float   f32x4;

struct KP {
  const float *W0,*b0,*W1,*b1,*W2,*b2,*W3,*b3,*W4,*b4,*W5,*b5,*W6,*b6;
  const float *bc1,*bc2,*bc3,*bc4,*bc5,*f1,*inp,*real;
  const unsigned short *Wfh,*Wfl;     // frag-ordered bf16 hi/lo W1..W5
  const unsigned short *W6fh,*W6fl;   // frag-ordered bf16 hi/lo W6 (N padded to 16)
  float *wsBC,*wsDA,*wsF;
};

__device__ __forceinline__ float ftanh(float a){
  float e = __expf(2.0f*a);
  return 1.0f - 2.0f/(e + 1.0f);
}
__device__ __forceinline__ void splitf(float v, unsigned short& h, unsigned short& l){
  unsigned int b = __float_as_uint(v);
  h = (unsigned short)(b >> 16);
  float lo = v - __uint_as_float(b & 0xFFFF0000u);
  l = (unsigned short)(__float_as_uint(lo) >> 16);
}
// A byte addr in [80][256] bf16 (row stride 512B), swizzled.
// f(row) uses row bits 0-3 so MFMA reads (row=..+lrow) stay minimal AND
// epilogue writes (row=..+q*4+r) put the 4 q-groups in 4 distinct 16B slots.
__device__ __forceinline__ int aswz(int row, int kbyte){
  int f = ((row & 7) ^ ((row & 8) >> 2)) << 4;
  return (row*512 + kbyte) ^ f;
}

// ---------------- prep: split W1..W5 (+W6 padded) into frag-ordered bf16 hi/lo ----------------
// frag order: [ks(8)][ntile][lane(64)][e(8)]; lane=((k&31)>>3)*16+(col&15), e=k&7
__global__ void prep_kernel(const float* W1, const float* W2, const float* W3,
                            const float* W4, const float* W5, const float* W6,
                            unsigned short* Wfh, unsigned short* Wfl,
                            unsigned short* W6fh, unsigned short* W6fl){
  int idx = blockIdx.x*256 + threadIdx.x;      // 0..331775
  if (idx < 327680){
    int li  = idx >> 16;
    int rem = idx & 65535;
    int k   = rem >> 8;
    int col = rem & 255;
    const float* Ws[5] = {W1,W2,W3,W4,W5};
    float v = Ws[li][k*256 + col];
    unsigned short hi, lo;
    splitf(v, hi, lo);
    int ks = k >> 5, kr = k & 31, qq = kr >> 3, e = kr & 7;
    int lane = qq*16 + (col & 15), nt = col >> 4;
    int pos = li*65536 + (ks*16 + nt)*512 + lane*8 + e;
    Wfh[pos] = hi; Wfl[pos] = lo;
  } else {
    int t = idx - 327680;            // 0..4095: [ks(8)][lane(64)][e(8)]
    int ks = t >> 9, lane = (t & 511) >> 3, e = t & 7;
    int k = ks*32 + (lane >> 4)*8 + e;
    int col = lane & 15;
    float v = (col < 4) ? W6[k*4 + col] : 0.f;
    unsigned short hi, lo;
    splitf(v, hi, lo);
    W6fh[t] = hi; W6fl[t] = lo;
  }
}

// ---------------- fused main kernel: 512 thr, M=80, N=256, MFMA 16x16x32 bf16 ----------------
__global__ __launch_bounds__(512,4) void fused_kernel(KP P, int nbP){
  __shared__ unsigned char Abuf[81920];   // hi [80][256]bf16 @0, lo @40960; union'd tail
  const int tid  = threadIdx.x;
  const int lane = tid & 63;
  const int wv   = tid >> 6;          // 0..7
  const int q    = lane >> 4;         // 0..3
  const int lrow = lane & 15;
  const bool isP = (int)blockIdx.x < nbP;
  const int bid  = isP ? (int)blockIdx.x : (int)blockIdx.x - nbP;

  // ---- layer 0 (2 -> 256), write A hi/lo ----
  {
    const int pt = tid >> 5;      // 0..15
    const int jg = tid & 31;      // 8-col group
    const int j0 = jg*8;
    float wz[8], wr[8], bb[8];
    #pragma unroll
    for (int jj=0;jj<8;++jj){ wz[jj]=P.W0[j0+jj]; wr[jj]=P.W0[256+j0+jj]; bb[jj]=P.b0[j0+jj]; }
    if (isP){
      int g = bid*16 + pt;
      float x0 = P.f1[2*g], x1 = P.f1[2*g+1];
      u16x8 hv[5], lv[5];
      #pragma unroll
      for (int jj=0;jj<8;++jj){
        float a = x0*wz[jj] + x1*wr[jj] + bb[jj];
        float t = ftanh(a), s = 1.f - t*t, cc = -2.f*t*s;
        float o[5] = {t, s*wz[jj], s*wr[jj], cc*wz[jj]*wz[jj], cc*wr[jj]*wr[jj]};
        #pragma unroll
        for (int s_=0;s_<5;++s_){ unsigned short h_,l_; splitf(o[s_],h_,l_); hv[s_][jj]=h_; lv[s_][jj]=l_; }
      }
      #pragma unroll
      for (int s_=0;s_<5;++s_){
        int byte = aswz(s_*16 + pt, jg*16);
        *(u16x8*)(Abuf + byte)         = hv[s_];
        *(u16x8*)(Abuf + 40960 + byte) = lv[s_];
      }
    } else {
      #pragma unroll
      for (int pp=0;pp<5;++pp){
        int row = pt + 16*pp;
        int g = bid*80 + row;
        float x0 = 0.f, x1 = 0.f;
        if (g < 37000){
          const float* src; int li2;
          if      (g <  1000){ src=P.bc1; li2=g; }
          else if (g <  2000){ src=P.bc2; li2=g-1000; }
          else if (g <  7000){ src=P.bc3; li2=g-2000; }
          else if (g < 12000){ src=P.bc4; li2=g-7000; }
          else if (g < 17000){ src=P.bc5; li2=g-12000; }
          else               { src=P.inp; li2=g-17000; }
          x0 = src[2*li2]; x1 = src[2*li2+1];
        }
        u16x8 hv, lv;
        #pragma unroll
        for (int jj=0;jj<8;++jj){
          float t = ftanh(x0*wz[jj] + x1*wr[jj] + bb[jj]);
          unsigned short h_,l_; splitf(t,h_,l_); hv[jj]=h_; lv[jj]=l_;
        }
        int byte = aswz(row, jg*16);
        *(u16x8*)(Abuf + byte)         = hv;
        *(u16x8*)(Abuf + 40960 + byte) = lv;
      }
    }
  }

  // ---- layers 1..5: C = A_hi*W_hi + A_hi*W_lo + A_lo*W_hi ----
  for (int li=0; li<5; ++li){
    const float* bl = (li==0)?P.b1:(li==1)?P.b2:(li==2)?P.b3:(li==3)?P.b4:P.b5;
    const unsigned short* WH = P.Wfh + li*65536;
    const unsigned short* WL = P.Wfl + li*65536;
    f32x4 acc[5][2];
    #pragma unroll
    for (int m=0;m<5;++m)
      #pragma unroll
      for (int n=0;n<2;++n){ acc[m][n][0]=0.f; acc[m][n][1]=0.f; acc[m][n][2]=0.f; acc[m][n][3]=0.f; }
    __syncthreads();   // A of previous layer visible
    #pragma unroll
    for (int ks=0; ks<8; ++ks){
      bf16x8 bh[2], bo[2], ah[5], al[5];
      #pragma unroll
      for (int n=0;n<2;++n){
        int idx = (ks*16 + (wv*2+n))*512 + lane*8;
        bh[n] = *(const bf16x8*)(WH + idx);
        bo[n] = *(const bf16x8*)(WL + idx);
      }
      #pragma unroll
      for (int m=0;m<5;++m){
        int byte = aswz(m*16 + lrow, ks*64 + q*16);
        ah[m] = *(const bf16x8*)(Abuf + byte);
        al[m] = *(const bf16x8*)(Abuf + 40960 + byte);
      }
      __builtin_amdgcn_s_setprio(1);
      #pragma unroll
      for (int m=0;m<5;++m)
        #pragma unroll
        for (int n=0;n<2;++n){
          acc[m][n] = __builtin_amdgcn_mfma_f32_16x16x32_bf16(ah[m], bh[n], acc[m][n], 0,0,0);
          acc[m][n] = __builtin_amdgcn_mfma_f32_16x16x32_bf16(ah[m], bo[n], acc[m][n], 0,0,0);
          acc[m][n] = __builtin_amdgcn_mfma_f32_16x16x32_bf16(al[m], bh[n], acc[m][n], 0,0,0);
        }
      __builtin_amdgcn_s_setprio(0);
    }
    __syncthreads();   // all A reads done before overwrite
    #pragma unroll
    for (int n=0;n<2;++n){
      int col = (wv*2+n)*16 + lrow;
      float bias = bl[col];
      #pragma unroll
      for (int r=0;r<4;++r){
        int rw = q*4 + r;
        if (isP){
          float a  = acc[0][n][r] + bias;
          float Dz = acc[1][n][r], Dr = acc[2][n][r];
          float Dzz= acc[3][n][r], Drr= acc[4][n][r];
          float t = ftanh(a), s = 1.f - t*t, cc = -2.f*t*s;
          float o[5] = {t, s*Dz, s*Dr, s*Dzz + cc*Dz*Dz, s*Drr + cc*Dr*Dr};
          #pragma unroll
          for (int s_=0;s_<5;++s_){
            int row = s_*16 + rw;
            unsigned short h_,l_; splitf(o[s_],h_,l_);
            *(unsigned short*)(Abuf + aswz(row, col*2)) = h_;
            *(unsigned short*)(Abuf + 40960 + aswz(row, col*2)) = l_;
          }
        } else {
          #pragma unroll
          for (int m=0;m<5;++m){
            int row = m*16 + rw;
            float t = ftanh(acc[m][n][r] + bias);
            unsigned short h_,l_; splitf(t,h_,l_);
            *(unsigned short*)(Abuf + aswz(row, col*2)) = h_;
            *(unsigned short*)(Abuf + 40960 + aswz(row, col*2)) = l_;
          }
        }
      }
    }
  }
  __syncthreads();   // layer-5 A visible

  // ---- layer 6 via MFMA: wave m (0..4) owns M-tile m, single N-tile (cols 0..3 valid) ----
  f32x4 a6; a6[0]=0.f; a6[1]=0.f; a6[2]=0.f; a6[3]=0.f;
  if (wv < 5){
    #pragma unroll
    for (int ks=0; ks<8; ++ks){
      bf16x8 bh = *(const bf16x8*)(P.W6fh + ks*512 + lane*8);
      bf16x8 bo = *(const bf16x8*)(P.W6fl + ks*512 + lane*8);
      int byte = aswz(wv*16 + lrow, ks*64 + q*16);
      bf16x8 ah = *(const bf16x8*)(Abuf + byte);
      bf16x8 al = *(const bf16x8*)(Abuf + 40960 + byte);
      a6 = __builtin_amdgcn_mfma_f32_16x16x32_bf16(ah, bh, a6, 0,0,0);
      a6 = __builtin_amdgcn_mfma_f32_16x16x32_bf16(ah, bo, a6, 0,0,0);
      a6 = __builtin_amdgcn_mfma_f32_16x16x32_bf16(al, bh, a6, 0,0,0);
    }
  }
  __syncthreads();   // all layer-6 A reads done; Abuf reusable as union

  float* fin  = (float*)Abuf;            // pde [16][20]; fwd [80][4]
  float* red  = (float*)(Abuf + 4096);
  float* redB = (float*)(Abuf + 6144);

  if (wv < 5 && lrow < 4){
    #pragma unroll
    for (int r=0;r<4;++r){
      if (isP){
        int pt = q*4 + r;
        float v = a6[r] + ((wv==0) ? P.b6[lrow] : 0.f);
        fin[pt*20 + wv*4 + lrow] = v;
      } else {
        int row = wv*16 + q*4 + r;
        fin[row*4 + lrow] = a6[r] + P.b6[lrow];
      }
    }
  }
  __syncthreads();

  // ---- loss terms ----
  if (isP){
    if (tid < 16){
      const float* F = &fin[tid*20];
      float r = P.f1[2*(bid*16 + tid) + 1];
      float uz=F[0],  us=F[1],  ur=F[2];
      float uz_z=F[4],us_z=F[5],ur_z=F[6],p_z=F[7];
      float uz_r=F[8],us_r=F[9],ur_r=F[10],p_r=F[11];
      float uz_zz=F[12],us_zz=F[13],ur_zz=F[14];
      float uz_rr=F[16],us_rr=F[17],ur_rr=F[18];
      float invr = 1.f/r;
      float eq1 = ur*ur_r + uz*ur_z - us*us*invr + p_r
                - NUC*invr*ur_r - NUC*ur_rr - NUC*ur_zz + NUC*ur*invr*invr;
      float eq2 = ur*us_r + uz*us_z + ur*us*invr
                - NUC*invr*us_r - NUC*us_rr - NUC*us_zz + NUC*us*invr*invr;
      float eq3 = ur*uz_r + uz*uz_z + p_z
                - NUC*invr*uz_r - NUC*uz_rr - NUC*uz_zz;
      float eq4 = ur + r*ur_r + r*uz_z;
      red[tid] = (eq1*eq1 + eq2*eq2 + eq3*eq3 + eq4*eq4) * (1.0f/80000.f);
    }
    __syncthreads();
    if (tid == 0){
      float s = 0.f;
      #pragma unroll
      for (int i=0;i<16;++i) s += red[i];
      P.wsF[bid] = s;
    }
  } else {
    if (tid < 80){
      float dj0 = fin[tid*4+0], dj1 = fin[tid*4+1];
      float dj2 = fin[tid*4+2], dj3 = fin[tid*4+3];
      float bcp = 0.f, dap = 0.f;
      int g = bid*80 + tid;
      if (g < 37000){
        if      (g <  2000){ bcp = (dj0*dj0 + dj1*dj1 + dj2*dj2)*(1.0f/1000.f); }
        else if (g <  7000){ float d1 = dj1 - 1.f;
                             bcp = (dj0*dj0 + d1*d1 + dj2*dj2)*(1.0f/5000.f); }
        else if (g < 12000){ bcp = (dj0*dj0 + dj1*dj1 + dj2*dj2)*(1.0f/5000.f); }
        else if (g < 17000){ bcp = dj3*dj3*(1.0f/5000.f); }
        else { const float* rr = P.real + (g-17000)*4;
               float e0=dj0-rr[0], e1=dj1-rr[1], e2=dj2-rr[2], e3=dj3-rr[3];
               dap = (e0*e0 + e1*e1 + e2*e2 + e3*e3)*(1.0f/80000.f); }
      }
      red[tid] = bcp; redB[tid] = dap;
    }
    __syncthreads();
    if (tid == 0){
      float sA=0.f, sB=0.f;
      #pragma unroll
      for (int i=0;i<80;++i){ sA += red[i]; sB += redB[i]; }
      P.wsBC[bid] = sA; P.wsDA[bid] = sB;
    }
  }
}

// ---------------- final deterministic reduction ----------------
__global__ void reduce_kernel(const float* wsBC, const float* wsDA, const float* wsF,
                              float* out, int nbBC, int nbP){
  __shared__ float sm[256];
  const int tid = threadIdx.x;
  float a;

  a = 0.f; for (int i=tid;i<nbBC;i+=256) a += wsBC[i];
  sm[tid]=a; __syncthreads();
  for (int off=128; off>0; off>>=1){ if (tid<off) sm[tid]+=sm[tid+off]; __syncthreads(); }
  if (tid==0) out[0]=sm[0];
  __syncthreads();

  a = 0.f; for (int i=tid;i<nbBC;i+=256) a += wsDA[i];
  sm[tid]=a; __syncthreads();
  for (int off=128; off>0; off>>=1){ if (tid<off) sm[tid]+=sm[tid+off]; __syncthreads(); }
  if (tid==0) out[1]=sm[0];
  __syncthreads();

  a = 0.f; for (int i=tid;i<nbP;i+=256) a += wsF[i];
  sm[tid]=a; __syncthreads();
  for (int off=128; off>0; off>>=1){ if (tid<off) sm[tid]+=sm[tid+off]; __syncthreads(); }
  if (tid==0) out[2]=sm[0];
}

extern "C" void kernel_launch(void* const* d_in, const int* in_sizes, int n_in,
                              void* d_out, int out_size, void* d_ws, size_t ws_size,
                              hipStream_t stream){
  KP P;
  P.W0=(const float*)d_in[0];  P.b0=(const float*)d_in[1];
  P.W1=(const float*)d_in[2];  P.b1=(const float*)d_in[3];
  P.W2=(const float*)d_in[4];  P.b2=(const float*)d_in[5];
  P.W3=(const float*)d_in[6];  P.b3=(const float*)d_in[7];
  P.W4=(const float*)d_in[8];  P.b4=(const float*)d_in[9];
  P.W5=(const float*)d_in[10]; P.b5=(const float*)d_in[11];
  P.W6=(const float*)d_in[12]; P.b6=(const float*)d_in[13];
  P.bc1=(const float*)d_in[14]; P.bc2=(const float*)d_in[15];
  P.bc3=(const float*)d_in[16]; P.bc4=(const float*)d_in[17];
  P.bc5=(const float*)d_in[18]; P.f1=(const float*)d_in[19];
  P.inp=(const float*)d_in[20]; P.real=(const float*)d_in[21];

  unsigned short* wf = (unsigned short*)d_ws;
  P.Wfh  = wf;                  // 327680 ush
  P.Wfl  = wf + 327680;         // 327680 ush
  P.W6fh = wf + 655360;         // 4096 ush
  P.W6fl = wf + 659456;         // 4096 ush
  float* pb = (float*)((char*)d_ws + 1327104);
  P.wsBC = pb; P.wsDA = pb + 512; P.wsF = pb + 1024;   // 463,463,1250 used

  const int nbP  = 20000 / 16;           // 1250 pde blocks (16 pts)
  const int nbBC = (37000 + 79) / 80;    // 463 fwd blocks (80 pts)

  prep_kernel<<<dim3(1296), dim3(256), 0, stream>>>(
      P.W1, P.W2, P.W3, P.W4, P.W5, P.W6,
      (unsigned short*)wf, (unsigned short*)(wf + 327680),
      (unsigned short*)(wf + 655360), (unsigned short*)(wf + 659456));
  fused_kernel<<<dim3(nbP + nbBC), dim3(512), 0, stream>>>(P, nbP);
  reduce_kernel<<<dim3(1), dim3(256), 0, stream>>>(P.wsBC, P.wsDA, P.wsF,
                                                   (float*)d_out, nbBC, nbP);
}

// Round 7
// 376.667 us; speedup vs baseline: 1.5508x; 1.5508x over previous
//
#include <hip/hip_runtime.h>

#define NUC 8.0e-4f   // MIU/(U*L)

typedef __attribute__((ext_vector_type(8))) short   bf16x8;
typedef __attribute__((ext_vector_type(8))) unsigned short u16x8;
typedef __attribute__((ext_vector_type(4))) float   f32x4;

struct KP {
  const float *W0,*b0,*W1,*b1,*W2,*b2,*W3,*b3,*W4,*b4,*W5,*b5,*W6,*b6;
  const float *bc1,*bc2,*bc3,*bc4,*bc5,*f1,*inp,*real;
  const unsigned short *Wfh,*Wfl;     // frag-ordered bf16 hi/lo W1..W5
  const unsigned short *W6fh,*W6fl;   // frag-ordered bf16 hi/lo W6 (N padded to 16)
  float *wsBC,*wsDA,*wsF;
};

__device__ __forceinline__ float ftanh(float a){
  float e = __expf(2.0f*a);
  return 1.0f - 2.0f/(e + 1.0f);
}
__device__ __forceinline__ void splitf(float v, unsigned short& h, unsigned short& l){
  unsigned int b = __float_as_uint(v);
  h = (unsigned short)(b >> 16);
  float lo = v - __uint_as_float(b & 0xFFFF0000u);
  l = (unsigned short)(__float_as_uint(lo) >> 16);
}
// A byte addr in [80][256] bf16 (row stride 512B), swizzled:
// reads (8 consecutive lrow) hit 8 distinct 16B slots; epilogue q-groups
// land in 4 distinct slots via the row&8 fold.
__device__ __forceinline__ int aswz(int row, int kbyte){
  int f = ((row & 7) ^ ((row & 8) >> 2)) << 4;
  return (row*512 + kbyte) ^ f;
}

// ---------------- prep: split W1..W5 (+W6 padded) into frag-ordered bf16 hi/lo ----------------
// frag order: [ks(8)][ntile][lane(64)][e(8)]; lane=((k&31)>>3)*16+(col&15), e=k&7
__global__ void prep_kernel(const float* W1, const float* W2, const float* W3,
                            const float* W4, const float* W5, const float* W6,
                            unsigned short* Wfh, unsigned short* Wfl,
                            unsigned short* W6fh, unsigned short* W6fl){
  int idx = blockIdx.x*256 + threadIdx.x;      // 0..331775
  if (idx < 327680){
    int li  = idx >> 16;
    int rem = idx & 65535;
    int k   = rem >> 8;
    int col = rem & 255;
    const float* Ws[5] = {W1,W2,W3,W4,W5};
    float v = Ws[li][k*256 + col];
    unsigned short hi, lo;
    splitf(v, hi, lo);
    int ks = k >> 5, kr = k & 31, qq = kr >> 3, e = kr & 7;
    int lane = qq*16 + (col & 15), nt = col >> 4;
    int pos = li*65536 + (ks*16 + nt)*512 + lane*8 + e;
    Wfh[pos] = hi; Wfl[pos] = lo;
  } else {
    int t = idx - 327680;            // 0..4095: [ks(8)][lane(64)][e(8)]
    int ks = t >> 9, lane = (t & 511) >> 3, e = t & 7;
    int k = ks*32 + (lane >> 4)*8 + e;
    int col = lane & 15;
    float v = (col < 4) ? W6[k*4 + col] : 0.f;
    unsigned short hi, lo;
    splitf(v, hi, lo);
    W6fh[t] = hi; W6fl[t] = lo;
  }
}

// ---------------- fused main kernel: 512 thr, M=80, N=256, MFMA 16x16x32 bf16 ----------------
__global__ __launch_bounds__(512,4) void fused_kernel(KP P, int nbP){
  __shared__ unsigned char Abuf[81920];   // hi [80][256]bf16 @0, lo @40960; union'd tail
  const int tid  = threadIdx.x;
  const int lane = tid & 63;
  const int wv   = tid >> 6;          // 0..7
  const int q    = lane >> 4;         // 0..3
  const int lrow = lane & 15;
  const bool isP = (int)blockIdx.x < nbP;
  const int bid  = isP ? (int)blockIdx.x : (int)blockIdx.x - nbP;

  // ---- layer 0 (2 -> 256), write A hi/lo ----
  {
    const int pt = tid >> 5;      // 0..15
    const int jg = tid & 31;      // 8-col group
    const int j0 = jg*8;
    float wz[8], wr[8], bb[8];
    #pragma unroll
    for (int jj=0;jj<8;++jj){ wz[jj]=P.W0[j0+jj]; wr[jj]=P.W0[256+j0+jj]; bb[jj]=P.b0[j0+jj]; }
    if (isP){
      int g = bid*16 + pt;
      float x0 = P.f1[2*g], x1 = P.f1[2*g+1];
      u16x8 hv[5], lv[5];
      #pragma unroll
      for (int jj=0;jj<8;++jj){
        float a = x0*wz[jj] + x1*wr[jj] + bb[jj];
        float t = ftanh(a), s = 1.f - t*t, cc = -2.f*t*s;
        float o[5] = {t, s*wz[jj], s*wr[jj], cc*wz[jj]*wz[jj], cc*wr[jj]*wr[jj]};
        #pragma unroll
        for (int s_=0;s_<5;++s_){ unsigned short h_,l_; splitf(o[s_],h_,l_); hv[s_][jj]=h_; lv[s_][jj]=l_; }
      }
      #pragma unroll
      for (int s_=0;s_<5;++s_){
        int byte = aswz(s_*16 + pt, jg*16);
        *(u16x8*)(Abuf + byte)         = hv[s_];
        *(u16x8*)(Abuf + 40960 + byte) = lv[s_];
      }
    } else {
      #pragma unroll
      for (int pp=0;pp<5;++pp){
        int row = pt + 16*pp;
        int g = bid*80 + row;
        float x0 = 0.f, x1 = 0.f;
        if (g < 37000){
          const float* src; int li2;
          if      (g <  1000){ src=P.bc1; li2=g; }
          else if (g <  2000){ src=P.bc2; li2=g-1000; }
          else if (g <  7000){ src=P.bc3; li2=g-2000; }
          else if (g < 12000){ src=P.bc4; li2=g-7000; }
          else if (g < 17000){ src=P.bc5; li2=g-12000; }
          else               { src=P.inp; li2=g-17000; }
          x0 = src[2*li2]; x1 = src[2*li2+1];
        }
        u16x8 hv, lv;
        #pragma unroll
        for (int jj=0;jj<8;++jj){
          float t = ftanh(x0*wz[jj] + x1*wr[jj] + bb[jj]);
          unsigned short h_,l_; splitf(t,h_,l_); hv[jj]=h_; lv[jj]=l_;
        }
        int byte = aswz(row, jg*16);
        *(u16x8*)(Abuf + byte)         = hv;
        *(u16x8*)(Abuf + 40960 + byte) = lv;
      }
    }
  }

  // ---- layers 1..5: C = A_hi*W_hi + A_hi*W_lo + A_lo*W_hi ----
  for (int li=0; li<5; ++li){
    const float* bl = (li==0)?P.b1:(li==1)?P.b2:(li==2)?P.b3:(li==3)?P.b4:P.b5;
    const unsigned short* WH = P.Wfh + li*65536;
    const unsigned short* WL = P.Wfl + li*65536;
    f32x4 acc[5][2];
    #pragma unroll
    for (int m=0;m<5;++m)
      #pragma unroll
      for (int n=0;n<2;++n){ acc[m][n][0]=0.f; acc[m][n][1]=0.f; acc[m][n][2]=0.f; acc[m][n][3]=0.f; }
    __syncthreads();   // A of previous layer visible
    #pragma unroll
    for (int ks=0; ks<8; ++ks){
      // B fragments for this wave's two N-tiles (global/L2)
      bf16x8 bh0, bo0, bh1, bo1;
      {
        int idx = (ks*16 + wv*2)*512 + lane*8;
        bh0 = *(const bf16x8*)(WH + idx);
        bo0 = *(const bf16x8*)(WL + idx);
        bh1 = *(const bf16x8*)(WH + idx + 512);
        bo1 = *(const bf16x8*)(WL + idx + 512);
      }
      __builtin_amdgcn_sched_group_barrier(0x020, 4, 0);   // 4 VMEM reads first
      __builtin_amdgcn_s_setprio(1);
      #pragma unroll
      for (int m=0;m<5;++m){
        int byte = aswz(m*16 + lrow, ks*64 + q*16);
        bf16x8 ah = *(const bf16x8*)(Abuf + byte);
        bf16x8 al = *(const bf16x8*)(Abuf + 40960 + byte);
        acc[m][0] = __builtin_amdgcn_mfma_f32_16x16x32_bf16(ah, bh0, acc[m][0], 0,0,0);
        acc[m][0] = __builtin_amdgcn_mfma_f32_16x16x32_bf16(ah, bo0, acc[m][0], 0,0,0);
        acc[m][0] = __builtin_amdgcn_mfma_f32_16x16x32_bf16(al, bh0, acc[m][0], 0,0,0);
        acc[m][1] = __builtin_amdgcn_mfma_f32_16x16x32_bf16(ah, bh1, acc[m][1], 0,0,0);
        acc[m][1] = __builtin_amdgcn_mfma_f32_16x16x32_bf16(ah, bo1, acc[m][1], 0,0,0);
        acc[m][1] = __builtin_amdgcn_mfma_f32_16x16x32_bf16(al, bh1, acc[m][1], 0,0,0);
        // keep only one m-tile's A fragments live: 2 DS reads then 6 MFMAs
        __builtin_amdgcn_sched_group_barrier(0x100, 2, 0);
        __builtin_amdgcn_sched_group_barrier(0x008, 6, 0);
      }
      __builtin_amdgcn_s_setprio(0);
    }
    __syncthreads();   // all A reads done before overwrite
    #pragma unroll
    for (int n=0;n<2;++n){
      int col = (wv*2+n)*16 + lrow;
      float bias = bl[col];
      #pragma unroll
      for (int r=0;r<4;++r){
        int rw = q*4 + r;
        if (isP){
          float a  = acc[0][n][r] + bias;
          float Dz = acc[1][n][r], Dr = acc[2][n][r];
          float Dzz= acc[3][n][r], Drr= acc[4][n][r];
          float t = ftanh(a), s = 1.f - t*t, cc = -2.f*t*s;
          float o[5] = {t, s*Dz, s*Dr, s*Dzz + cc*Dz*Dz, s*Drr + cc*Dr*Dr};
          #pragma unroll
          for (int s_=0;s_<5;++s_){
            int row = s_*16 + rw;
            unsigned short h_,l_; splitf(o[s_],h_,l_);
            *(unsigned short*)(Abuf + aswz(row, col*2)) = h_;
            *(unsigned short*)(Abuf + 40960 + aswz(row, col*2)) = l_;
          }
        } else {
          #pragma unroll
          for (int m=0;m<5;++m){
            int row = m*16 + rw;
            float t = ftanh(acc[m][n][r] + bias);
            unsigned short h_,l_; splitf(t,h_,l_);
            *(unsigned short*)(Abuf + aswz(row, col*2)) = h_;
            *(unsigned short*)(Abuf + 40960 + aswz(row, col*2)) = l_;
          }
        }
      }
    }
  }
  __syncthreads();   // layer-5 A visible

  // ---- layer 6 via MFMA: wave m (0..4) owns M-tile m, single N-tile (cols 0..3 valid) ----
  f32x4 a6; a6[0]=0.f; a6[1]=0.f; a6[2]=0.f; a6[3]=0.f;
  if (wv < 5){
    #pragma unroll
    for (int ks=0; ks<8; ++ks){
      bf16x8 bh = *(const bf16x8*)(P.W6fh + ks*512 + lane*8);
      bf16x8 bo = *(const bf16x8*)(P.W6fl + ks*512 + lane*8);
      int byte = aswz(wv*16 + lrow, ks*64 + q*16);
      bf16x8 ah = *(const bf16x8*)(Abuf + byte);
      bf16x8 al = *(const bf16x8*)(Abuf + 40960 + byte);
      a6 = __builtin_amdgcn_mfma_f32_16x16x32_bf16(ah, bh, a6, 0,0,0);
      a6 = __builtin_amdgcn_mfma_f32_16x16x32_bf16(ah, bo, a6, 0,0,0);
      a6 = __builtin_amdgcn_mfma_f32_16x16x32_bf16(al, bh, a6, 0,0,0);
    }
  }
  __syncthreads();   // all layer-6 A reads done; Abuf reusable as union

  float* fin  = (float*)Abuf;            // pde [16][20]; fwd [80][4]
  float* red  = (float*)(Abuf + 4096);
  float* redB = (float*)(Abuf + 6144);

  if (wv < 5 && lrow < 4){
    #pragma unroll
    for (int r=0;r<4;++r){
      if (isP){
        int pt = q*4 + r;
        float v = a6[r] + ((wv==0) ? P.b6[lrow] : 0.f);
        fin[pt*20 + wv*4 + lrow] = v;
      } else {
        int row = wv*16 + q*4 + r;
        fin[row*4 + lrow] = a6[r] + P.b6[lrow];
      }
    }
  }
  __syncthreads();

  // ---- loss terms ----
  if (isP){
    if (tid < 16){
      const float* F = &fin[tid*20];
      float r = P.f1[2*(bid*16 + tid) + 1];
      float uz=F[0],  us=F[1],  ur=F[2];
      float uz_z=F[4],us_z=F[5],ur_z=F[6],p_z=F[7];
      float uz_r=F[8],us_r=F[9],ur_r=F[10],p_r=F[11];
      float uz_zz=F[12],us_zz=F[13],ur_zz=F[14];
      float uz_rr=F[16],us_rr=F[17],ur_rr=F[18];
      float invr = 1.f/r;
      float eq1 = ur*ur_r + uz*ur_z - us*us*invr + p_r
                - NUC*invr*ur_r - NUC*ur_rr - NUC*ur_zz + NUC*ur*invr*invr;
      float eq2 = ur*us_r + uz*us_z + ur*us*invr
                - NUC*invr*us_r - NUC*us_rr - NUC*us_zz + NUC*us*invr*invr;
      float eq3 = ur*uz_r + uz*uz_z + p_z
                - NUC*invr*uz_r - NUC*uz_rr - NUC*uz_zz;
      float eq4 = ur + r*ur_r + r*uz_z;
      red[tid] = (eq1*eq1 + eq2*eq2 + eq3*eq3 + eq4*eq4) * (1.0f/80000.f);
    }
    __syncthreads();
    if (tid == 0){
      float s = 0.f;
      #pragma unroll
      for (int i=0;i<16;++i) s += red[i];
      P.wsF[bid] = s;
    }
  } else {
    if (tid < 80){
      float dj0 = fin[tid*4+0], dj1 = fin[tid*4+1];
      float dj2 = fin[tid*4+2], dj3 = fin[tid*4+3];
      float bcp = 0.f, dap = 0.f;
      int g = bid*80 + tid;
      if (g < 37000){
        if      (g <  2000){ bcp = (dj0*dj0 + dj1*dj1 + dj2*dj2)*(1.0f/1000.f); }
        else if (g <  7000){ float d1 = dj1 - 1.f;
                             bcp = (dj0*dj0 + d1*d1 + dj2*dj2)*(1.0f/5000.f); }
        else if (g < 12000){ bcp = (dj0*dj0 + dj1*dj1 + dj2*dj2)*(1.0f/5000.f); }
        else if (g < 17000){ bcp = dj3*dj3*(1.0f/5000.f); }
        else { const float* rr = P.real + (g-17000)*4;
               float e0=dj0-rr[0], e1=dj1-rr[1], e2=dj2-rr[2], e3=dj3-rr[3];
               dap = (e0*e0 + e1*e1 + e2*e2 + e3*e3)*(1.0f/80000.f); }
      }
      red[tid] = bcp; redB[tid] = dap;
    }
    __syncthreads();
    if (tid == 0){
      float sA=0.f, sB=0.f;
      #pragma unroll
      for (int i=0;i<80;++i){ sA += red[i]; sB += redB[i]; }
      P.wsBC[bid] = sA; P.wsDA[bid] = sB;
    }
  }
}

// ---------------- final deterministic reduction ----------------
__global__ void reduce_kernel(const float* wsBC, const float* wsDA, const float* wsF,
                              float* out, int nbBC, int nbP){
  __shared__ float sm[256];
  const int tid = threadIdx.x;
  float a;

  a = 0.f; for (int i=tid;i<nbBC;i+=256) a += wsBC[i];
  sm[tid]=a; __syncthreads();
  for (int off=128; off>0; off>>=1){ if (tid<off) sm[tid]+=sm[tid+off]; __syncthreads(); }
  if (tid==0) out[0]=sm[0];
  __syncthreads();

  a = 0.f; for (int i=tid;i<nbBC;i+=256) a += wsDA[i];
  sm[tid]=a; __syncthreads();
  for (int off=128; off>0; off>>=1){ if (tid<off) sm[tid]+=sm[tid+off]; __syncthreads(); }
  if (tid==0) out[1]=sm[0];
  __syncthreads();

  a = 0.f; for (int i=tid;i<nbP;i+=256) a += wsF[i];
  sm[tid]=a; __syncthreads();
  for (int off=128; off>0; off>>=1){ if (tid<off) sm[tid]+=sm[tid+off]; __syncthreads(); }
  if (tid==0) out[2]=sm[0];
}

extern "C" void kernel_launch(void* const* d_in, const int* in_sizes, int n_in,
                              void* d_out, int out_size, void* d_ws, size_t ws_size,
                              hipStream_t stream){
  KP P;
  P.W0=(const float*)d_in[0];  P.b0=(const float*)d_in[1];
  P.W1=(const float*)d_in[2];  P.b1=(const float*)d_in[3];
  P.W2=(const float*)d_in[4];  P.b2=(const float*)d_in[5];
  P.W3=(const float*)d_in[6];  P.b3=(const float*)d_in[7];
  P.W4=(const float*)d_in[8];  P.b4=(const float*)d_in[9];
  P.W5=(const float*)d_in[10]; P.b5=(const float*)d_in[11];
  P.W6=(const float*)d_in[12]; P.b6=(const float*)d_in[13];
  P.bc1=(const float*)d_in[14]; P.bc2=(const float*)d_in[15];
  P.bc3=(const float*)d_in[16]; P.bc4=(const float*)d_in[17];
  P.bc5=(const float*)d_in[18]; P.f1=(const float*)d_in[19];
  P.inp=(const float*)d_in[20]; P.real=(const float*)d_in[21];

  unsigned short* wf = (unsigned short*)d_ws;
  P.Wfh  = wf;                  // 327680 ush
  P.Wfl  = wf + 327680;         // 327680 ush
  P.W6fh = wf + 655360;         // 4096 ush
  P.W6fl = wf + 659456;         // 4096 ush
  float* pb = (float*)((char*)d_ws + 1327104);
  P.wsBC = pb; P.wsDA = pb + 512; P.wsF = pb + 1024;   // 463,463,1250 used

  const int nbP  = 20000 / 16;           // 1250 pde blocks (16 pts)
  const int nbBC = (37000 + 79) / 80;    // 463 fwd blocks (80 pts)

  prep_kernel<<<dim3(1296), dim3(256), 0, stream>>>(
      P.W1, P.W2, P.W3, P.W4, P.W5, P.W6,
      (unsigned short*)wf, (unsigned short*)(wf + 327680),
      (unsigned short*)(wf + 655360), (unsigned short*)(wf + 659456));
  fused_kernel<<<dim3(nbP + nbBC), dim3(512), 0, stream>>>(P, nbP);
  reduce_kernel<<<dim3(1), dim3(256), 0, stream>>>(P.wsBC, P.wsDA, P.wsF,
                                                   (float*)d_out, nbBC, nbP);
}